// Round 1
// baseline (131.651 us; speedup 1.0000x reference)
//
#include <hip/hip_runtime.h>
#include <cmath>

#define NB 16
#define NA 5
#define NH 152
#define NW 152
#define NT 50
#define NC 20
#define CH (6 + NC)    // 26 prediction channels
#define TCH (13 + NC)  // 33 target channels

// anchors / SCALE: (16,16),(32,32),(64,64),(96,48),(48,96) / 4
__device__ __constant__ float c_aw[NA] = {4.f, 8.f, 16.f, 24.f, 12.f};
__device__ __constant__ float c_ah[NA] = {4.f, 8.f, 16.f, 12.f, 24.f};

// packed target word:
//  bits 0-7   : gi
//  bits 8-15  : gj
//  bits 16-20 : ignore anchor mask (iou > 0.5)
//  bits 21-25 : best_n one-hot
//  bit  26    : valid
#define VALID_BIT (1u << 26)

// ws float slots: 0..3 sx,sy,sw,sh  4 s_ce  5 n_obj  6 s_obj_bce  7 s_noobj_bce  8 c_noobj
// packed words at ws + 64 floats

__global__ __launch_bounds__(1024) void k_targets(
    const float* __restrict__ pred, const float* __restrict__ tgt,
    const int* __restrict__ tsz, float* __restrict__ acc,
    unsigned int* __restrict__ packed_out) {
  __shared__ unsigned int s_packed[NB * NT];
  __shared__ float s_acc[6];
  const int tid = threadIdx.x;
  if (tid < 6) s_acc[tid] = 0.f;

  const int b = tid / NT;
  const int t = tid - b * NT;
  unsigned int word = 0;
  int gi = 0, gj = 0, bestn = 0, label = 0;
  float txv = 0, tyv = 0, twv = 0, thv = 0;
  bool valid = false;

  if (tid < NB * NT) {
    const float* tr = tgt + (size_t)tid * TCH;
    const float gx = tr[0] * 0.25f, gy = tr[1] * 0.25f;
    const float gh = tr[3] * 0.25f, gw = tr[4] * 0.25f;
    valid = (t < tsz[b]) && (gw > 0.f) && (gh > 0.f);
    gi = min(max((int)gx, 0), NW - 1);
    gj = min(max((int)gy, 0), NH - 1);
    const float area_gt = (gw + 1.f) * (gh + 1.f);
    float best = -1.f;
    unsigned amask = 0;
    for (int a = 0; a < NA; ++a) {
      const float inter = (fminf(gw, c_aw[a]) + 1.f) * (fminf(gh, c_ah[a]) + 1.f);
      const float area_a = (c_aw[a] + 1.f) * (c_ah[a] + 1.f);
      const float iou = inter / (area_gt + area_a - inter + 1e-16f);
      if (iou > best) { best = iou; bestn = a; }   // first-max tie-break
      if (iou > 0.5f) amask |= (1u << a);
    }
    txv = atanhf(gx - ((float)gi + 0.5f));
    tyv = atanhf(gy - ((float)gj + 0.5f));
    twv = logf(gw / c_aw[bestn] + 1e-16f);
    thv = logf(gh / c_ah[bestn] + 1e-16f);
    float bc = tr[13];
    label = 0;
    for (int c = 1; c < NC; ++c)
      if (tr[13 + c] > bc) { bc = tr[13 + c]; label = c; }
    if (valid)
      word = (unsigned)gi | ((unsigned)gj << 8) | (amask << 16) |
             (1u << (21 + bestn)) | VALID_BIT;
    s_packed[tid] = word;
    packed_out[tid] = word;
  }
  __syncthreads();

  // last-update-wins dedupe: winner iff no later valid target hits same (cell, anchor)
  bool winner = false;
  if (valid) {
    winner = true;
    const unsigned keymask = 0xFFFFu | (0x1Fu << 21);
    const unsigned mykey = word & keymask;
    for (int t2 = t + 1; t2 < NT; ++t2) {
      const unsigned w2 = s_packed[b * NT + t2];
      if ((w2 & VALID_BIT) && ((w2 & keymask) == mykey)) { winner = false; break; }
    }
  }

  float cx = 0, cy = 0, cw = 0, chh = 0, cce = 0, cn = 0;
  if (winner) {
    const size_t cell = ((((size_t)b * NA + bestn) * NH + gj) * NW + gi) * CH;
    const float* p = pred + cell;
    const float px = p[1], py = p[2], ph = p[4], pw = p[5];
    cx = (px - txv) * (px - txv);
    cy = (py - tyv) * (py - tyv);
    cw = (pw - twv) * (pw - twv);
    chh = (ph - thv) * (ph - thv);
    float m = p[6];
    for (int c = 1; c < NC; ++c) m = fmaxf(m, p[6 + c]);
    float s = 0.f;
    for (int c = 0; c < NC; ++c) s += expf(p[6 + c] - m);
    cce = (m + logf(s)) - p[6 + label];
    cn = 1.f;
  }

  // wave (64) shuffle reduce, then LDS atomics from lane 0 of each wave
  for (int off = 32; off >= 1; off >>= 1) {
    cx  += __shfl_down(cx, off, 64);
    cy  += __shfl_down(cy, off, 64);
    cw  += __shfl_down(cw, off, 64);
    chh += __shfl_down(chh, off, 64);
    cce += __shfl_down(cce, off, 64);
    cn  += __shfl_down(cn, off, 64);
  }
  if ((tid & 63) == 0) {
    atomicAdd(&s_acc[0], cx);
    atomicAdd(&s_acc[1], cy);
    atomicAdd(&s_acc[2], cw);
    atomicAdd(&s_acc[3], chh);
    atomicAdd(&s_acc[4], cce);
    atomicAdd(&s_acc[5], cn);
  }
  __syncthreads();
  if (tid < 6) acc[tid] = s_acc[tid];
  if (tid >= 6 && tid < 16) acc[tid] = 0.f;  // zero slots for the conf pass
}

__global__ __launch_bounds__(256) void k_conf(
    const float* __restrict__ pred, const unsigned int* __restrict__ packed,
    float* __restrict__ acc) {
  const int blk = blockIdx.x;  // b*NH + j
  const int b = blk / NH;
  const int j = blk - b * NH;

  __shared__ unsigned int s_match[NT];
  __shared__ int s_cnt;
  __shared__ float s_red[3][4];
  if (threadIdx.x == 0) {
    int cnt = 0;
    for (int t = 0; t < NT; ++t) {
      const unsigned w = packed[b * NT + t];
      if ((w & VALID_BIT) && (((w >> 8) & 0xFFu) == (unsigned)j)) s_match[cnt++] = w;
    }
    s_cnt = cnt;
  }
  __syncthreads();
  const int cnt = s_cnt;

  float s_ob = 0.f, s_nob = 0.f, c_nob = 0.f;
  for (int c = threadIdx.x; c < NA * NW; c += 256) {
    const int a = c / NW;
    const int i = c - a * NW;
    bool msk = false, ign = false;
    for (int m = 0; m < cnt; ++m) {
      const unsigned w = s_match[m];
      if ((w & 0xFFu) == (unsigned)i) {
        if (w & (1u << (21 + a))) msk = true;
        if (w & (1u << (16 + a))) ign = true;
      }
    }
    const float l = pred[((((size_t)b * NA + a) * NH + j) * NW + i) * CH];
    const float bce = fmaxf(l, 0.f) - (msk ? l : 0.f) + log1pf(expf(-fabsf(l)));
    if (msk) s_ob += bce;
    else if (!ign) { s_nob += bce; c_nob += 1.f; }
  }

  for (int off = 32; off >= 1; off >>= 1) {
    s_ob  += __shfl_down(s_ob, off, 64);
    s_nob += __shfl_down(s_nob, off, 64);
    c_nob += __shfl_down(c_nob, off, 64);
  }
  const int wave = threadIdx.x >> 6;
  if ((threadIdx.x & 63) == 0) {
    s_red[0][wave] = s_ob; s_red[1][wave] = s_nob; s_red[2][wave] = c_nob;
  }
  __syncthreads();
  if (threadIdx.x == 0) {
    float a0 = 0, a1 = 0, a2 = 0;
    for (int wv = 0; wv < 4; ++wv) { a0 += s_red[0][wv]; a1 += s_red[1][wv]; a2 += s_red[2][wv]; }
    atomicAdd(&acc[6], a0);
    atomicAdd(&acc[7], a1);
    atomicAdd(&acc[8], a2);
  }
}

__global__ void k_final(const float* __restrict__ acc, float* __restrict__ out) {
  const float n_obj = fmaxf(acc[5], 1.f);
  const float n_noobj = fmaxf(acc[8], 1.f);
  out[0] = (acc[0] + acc[1] + acc[2] + acc[3] + acc[4] + acc[6]) / n_obj +
           1.25f * acc[7] / n_noobj;
}

extern "C" void kernel_launch(void* const* d_in, const int* in_sizes, int n_in,
                              void* d_out, int out_size, void* d_ws, size_t ws_size,
                              hipStream_t stream) {
  const float* pred = (const float*)d_in[0];
  const float* tgt = (const float*)d_in[1];
  const int* tsz = (const int*)d_in[2];
  float* out = (float*)d_out;
  float* acc = (float*)d_ws;                       // 16 floats
  unsigned int* packed = (unsigned int*)((char*)d_ws + 64 * sizeof(float));

  k_targets<<<1, 1024, 0, stream>>>(pred, tgt, tsz, acc, packed);
  k_conf<<<NB * NH, 256, 0, stream>>>(pred, packed, acc);
  k_final<<<1, 1, 0, stream>>>(acc, out);
}

// Round 2
// 68.967 us; speedup vs baseline: 1.9089x; 1.9089x over previous
//
#include <hip/hip_runtime.h>
#include <cmath>

#define NB 16
#define NA 5
#define NH 152
#define NW 152
#define NT 50
#define NC 20
#define CH (6 + NC)    // 26 prediction channels
#define TCH (13 + NC)  // 33 target channels
#define ROWF (NW * CH) // 3952 floats per (b,a,j) row
#define ROWF4 (ROWF / 4) // 988 float4 per row
#define NBUCKET 64
#define BSTRIDE 16     // floats per bucket (64B padding -> no same-line atomics)

// anchors / SCALE: (16,16),(32,32),(64,64),(96,48),(48,96) / 4
__device__ __constant__ float c_aw[NA] = {4.f, 8.f, 16.f, 24.f, 12.f};
__device__ __constant__ float c_ah[NA] = {4.f, 8.f, 16.f, 12.f, 24.f};

// packed target word:
//  bits 0-7   : gi
//  bits 8-15  : gj
//  bits 16-20 : ignore anchor mask (iou > 0.5)
//  bits 21-25 : best_n one-hot
//  bit  26    : valid
#define VALID_BIT (1u << 26)

// ws float layout: [0..15] acc (0..3 sx,sy,sw,sh; 4 s_ce; 5 n_obj)
//                  [64..864) packed words (800)
//                  [1024..2048) buckets: 64 x 16 floats (slots 0..2 used)

__global__ __launch_bounds__(1024) void k_targets(
    const float* __restrict__ pred, const float* __restrict__ tgt,
    const int* __restrict__ tsz, float* __restrict__ acc,
    unsigned int* __restrict__ packed_out, float* __restrict__ buckets) {
  __shared__ unsigned int s_packed[NB * NT];
  __shared__ float s_acc[6];
  const int tid = threadIdx.x;
  if (tid < 6) s_acc[tid] = 0.f;
  buckets[tid] = 0.f;  // zero all 64*16 bucket floats (1024 threads)

  const int b = tid / NT;
  const int t = tid - b * NT;
  unsigned int word = 0;
  int gi = 0, gj = 0, bestn = 0, label = 0;
  float txv = 0, tyv = 0, twv = 0, thv = 0;
  bool valid = false;

  if (tid < NB * NT) {
    const float* tr = tgt + (size_t)tid * TCH;
    const float gx = tr[0] * 0.25f, gy = tr[1] * 0.25f;
    const float gh = tr[3] * 0.25f, gw = tr[4] * 0.25f;
    valid = (t < tsz[b]) && (gw > 0.f) && (gh > 0.f);
    gi = min(max((int)gx, 0), NW - 1);
    gj = min(max((int)gy, 0), NH - 1);
    const float area_gt = (gw + 1.f) * (gh + 1.f);
    float best = -1.f;
    unsigned amask = 0;
    for (int a = 0; a < NA; ++a) {
      const float inter = (fminf(gw, c_aw[a]) + 1.f) * (fminf(gh, c_ah[a]) + 1.f);
      const float area_a = (c_aw[a] + 1.f) * (c_ah[a] + 1.f);
      const float iou = inter / (area_gt + area_a - inter + 1e-16f);
      if (iou > best) { best = iou; bestn = a; }   // first-max tie-break
      if (iou > 0.5f) amask |= (1u << a);
    }
    txv = atanhf(gx - ((float)gi + 0.5f));
    tyv = atanhf(gy - ((float)gj + 0.5f));
    twv = logf(gw / c_aw[bestn] + 1e-16f);
    thv = logf(gh / c_ah[bestn] + 1e-16f);
    float bc = tr[13];
    label = 0;
    for (int c = 1; c < NC; ++c)
      if (tr[13 + c] > bc) { bc = tr[13 + c]; label = c; }
    if (valid)
      word = (unsigned)gi | ((unsigned)gj << 8) | (amask << 16) |
             (1u << (21 + bestn)) | VALID_BIT;
    s_packed[tid] = word;
    packed_out[tid] = word;
  }
  __syncthreads();

  // last-update-wins dedupe: winner iff no later valid target hits same (cell, anchor)
  bool winner = false;
  if (valid) {
    winner = true;
    const unsigned keymask = 0xFFFFu | (0x1Fu << 21);
    const unsigned mykey = word & keymask;
    for (int t2 = t + 1; t2 < NT; ++t2) {
      const unsigned w2 = s_packed[b * NT + t2];
      if ((w2 & VALID_BIT) && ((w2 & keymask) == mykey)) { winner = false; break; }
    }
  }

  float cx = 0, cy = 0, cw = 0, chh = 0, cce = 0, cn = 0;
  if (winner) {
    const size_t cell = ((((size_t)b * NA + bestn) * NH + gj) * NW + gi) * CH;
    const float* p = pred + cell;
    const float px = p[1], py = p[2], ph = p[4], pw = p[5];
    cx = (px - txv) * (px - txv);
    cy = (py - tyv) * (py - tyv);
    cw = (pw - twv) * (pw - twv);
    chh = (ph - thv) * (ph - thv);
    float m = p[6];
    for (int c = 1; c < NC; ++c) m = fmaxf(m, p[6 + c]);
    float s = 0.f;
    for (int c = 0; c < NC; ++c) s += expf(p[6 + c] - m);
    cce = (m + logf(s)) - p[6 + label];
    cn = 1.f;
  }

  for (int off = 32; off >= 1; off >>= 1) {
    cx  += __shfl_down(cx, off, 64);
    cy  += __shfl_down(cy, off, 64);
    cw  += __shfl_down(cw, off, 64);
    chh += __shfl_down(chh, off, 64);
    cce += __shfl_down(cce, off, 64);
    cn  += __shfl_down(cn, off, 64);
  }
  if ((tid & 63) == 0) {
    atomicAdd(&s_acc[0], cx);
    atomicAdd(&s_acc[1], cy);
    atomicAdd(&s_acc[2], cw);
    atomicAdd(&s_acc[3], chh);
    atomicAdd(&s_acc[4], cce);
    atomicAdd(&s_acc[5], cn);
  }
  __syncthreads();
  if (tid < 6) acc[tid] = s_acc[tid];
}

// One block per (b,a,j) row: fully-coalesced float4 stream of the 3952-float
// row; conf channel extracted via incremental mod-26 tracking.
__global__ __launch_bounds__(256) void k_conf(
    const float* __restrict__ pred, const unsigned int* __restrict__ packed,
    float* __restrict__ buckets) {
  const int blk = blockIdx.x;             // ((b*NA)+a)*NH + j
  const int b = blk / (NA * NH);
  const int rem = blk - b * NA * NH;
  const int a = rem / NH;
  const int j = rem - a * NH;

  __shared__ unsigned int s_match[NT];
  __shared__ int s_cnt;
  __shared__ float s_red[3][4];
  if (threadIdx.x == 0) s_cnt = 0;
  __syncthreads();
  if (threadIdx.x < NT) {
    const unsigned w = packed[b * NT + threadIdx.x];
    if ((w & VALID_BIT) && (((w >> 8) & 0xFFu) == (unsigned)j)) {
      // keep only targets that affect THIS anchor (mask or ignore bit set)
      if (w & ((1u << (21 + a)) | (1u << (16 + a)))) {
        int pos = atomicAdd(&s_cnt, 1);
        s_match[pos] = w;
      }
    }
  }
  __syncthreads();
  const int cnt = s_cnt;

  const float4* row = (const float4*)(pred + (size_t)blk * ROWF);
  float s_ob = 0.f, s_nob = 0.f, c_nob = 0.f;
  int q = threadIdx.x;       // float4 index in row
  int f0 = 4 * q;
  int ci = f0 / 26;          // cell index of float f0
  int m = f0 - 26 * ci;      // f0 mod 26
  #pragma unroll
  for (int k = 0; k < 4; ++k) {
    if (q < ROWF4) {
      const float4 v = row[q];
      int cell = -1;
      float l = 0.f;
      if (m == 0) { cell = ci; l = v.x; }
      else if (m >= 23) {      // m+e == 26 for e = 26-m in {1,2,3}
        const int e = 26 - m;
        cell = ci + 1;
        l = (e == 1) ? v.y : ((e == 2) ? v.z : v.w);
      }
      if (cell >= 0) {
        bool msk = false, ign = false;
        for (int t = 0; t < cnt; ++t) {
          const unsigned w = s_match[t];
          if ((w & 0xFFu) == (unsigned)cell) {
            msk |= ((w >> (21 + a)) & 1u) != 0u;
            ign |= ((w >> (16 + a)) & 1u) != 0u;
          }
        }
        const float bce = fmaxf(l, 0.f) - (msk ? l : 0.f) + log1pf(expf(-fabsf(l)));
        if (msk) s_ob += bce;
        else if (!ign) { s_nob += bce; c_nob += 1.f; }
      }
    }
    q += 256;
    ci += 39; m += 10;         // f += 1024 = 26*39 + 10
    if (m >= 26) { m -= 26; ++ci; }
  }

  for (int off = 32; off >= 1; off >>= 1) {
    s_ob  += __shfl_down(s_ob, off, 64);
    s_nob += __shfl_down(s_nob, off, 64);
    c_nob += __shfl_down(c_nob, off, 64);
  }
  const int wave = threadIdx.x >> 6;
  if ((threadIdx.x & 63) == 0) {
    s_red[0][wave] = s_ob; s_red[1][wave] = s_nob; s_red[2][wave] = c_nob;
  }
  __syncthreads();
  if (threadIdx.x == 0) {
    float a0 = 0, a1 = 0, a2 = 0;
    for (int wv = 0; wv < 4; ++wv) { a0 += s_red[0][wv]; a1 += s_red[1][wv]; a2 += s_red[2][wv]; }
    float* bk = buckets + (size_t)(blk & (NBUCKET - 1)) * BSTRIDE;
    atomicAdd(bk + 0, a0);
    atomicAdd(bk + 1, a1);
    atomicAdd(bk + 2, a2);
  }
}

__global__ void k_final(const float* __restrict__ acc,
                        const float* __restrict__ buckets,
                        float* __restrict__ out) {
  const int t = threadIdx.x;  // 64 threads
  float a0 = buckets[t * BSTRIDE + 0];
  float a1 = buckets[t * BSTRIDE + 1];
  float a2 = buckets[t * BSTRIDE + 2];
  for (int off = 32; off >= 1; off >>= 1) {
    a0 += __shfl_down(a0, off, 64);
    a1 += __shfl_down(a1, off, 64);
    a2 += __shfl_down(a2, off, 64);
  }
  if (t == 0) {
    const float n_obj = fmaxf(acc[5], 1.f);
    const float n_noobj = fmaxf(a2, 1.f);
    out[0] = (acc[0] + acc[1] + acc[2] + acc[3] + acc[4] + a0) / n_obj +
             1.25f * a1 / n_noobj;
  }
}

extern "C" void kernel_launch(void* const* d_in, const int* in_sizes, int n_in,
                              void* d_out, int out_size, void* d_ws, size_t ws_size,
                              hipStream_t stream) {
  const float* pred = (const float*)d_in[0];
  const float* tgt = (const float*)d_in[1];
  const int* tsz = (const int*)d_in[2];
  float* out = (float*)d_out;
  float* acc = (float*)d_ws;                                   // 16 floats
  unsigned int* packed = (unsigned int*)((float*)d_ws + 64);   // 800 words
  float* buckets = (float*)d_ws + 1024;                        // 64*16 floats

  k_targets<<<1, 1024, 0, stream>>>(pred, tgt, tsz, acc, packed, buckets);
  k_conf<<<NB * NA * NH, 256, 0, stream>>>(pred, packed, buckets);
  k_final<<<1, 64, 0, stream>>>(acc, buckets, out);
}